// Round 4
// baseline (386.504 us; speedup 1.0000x reference)
//
#include <hip/hip_runtime.h>

// RUM cell, algebraically reduced:
//   R @ h = h + (cos-1)(a u + b v) + sin (a v - b u),  a = u.h, b = v.h
//   hidden_new = assoc_mem @ (R @ h)   -- batched matvec, reads 256MB once
// Shapes fixed: B=256, IN=512, H=512, 3H=1536.
// Round 4: matvec split to 512-thr blocks x 2/CU, software-pipelined q-loop;
//          epilogue separated. Discriminates "stage-2 stalls" vs "HBM floor".

#define EPSF 1e-12f

typedef float vfloat4 __attribute__((ext_vector_type(4)));

// ---------------- block-wide float4 sum, 512 threads = 8 waves ----------
__device__ __forceinline__ float4 block_reduce4_512(float4 v, float4* red, int t) {
    __syncthreads();                 // protect red reuse across calls
#pragma unroll
    for (int off = 32; off >= 1; off >>= 1) {
        v.x += __shfl_xor(v.x, off, 64);
        v.y += __shfl_xor(v.y, off, 64);
        v.z += __shfl_xor(v.z, off, 64);
        v.w += __shfl_xor(v.w, off, 64);
    }
    if ((t & 63) == 0) red[t >> 6] = v;
    __syncthreads();
    float4 s = {0.f, 0.f, 0.f, 0.f};
#pragma unroll
    for (int i = 0; i < 8; ++i) {
        float4 r = red[i];
        s.x += r.x; s.y += r.y; s.z += r.z; s.w += r.w;
    }
    return s;
}

// ---------------- K1: proj = [inp|hid] @ [W_ih|W_hh]^T + b_ih + b_hh ----
// BM=32, BN=64, BK=32, 256 thr, 2x4 micro, register prefetch of next chunk.
__global__ __launch_bounds__(256) void gemm_proj(
    const float* __restrict__ inp, const float* __restrict__ hid,
    const float* __restrict__ W_ih, const float* __restrict__ W_hh,
    const float* __restrict__ b_ih, const float* __restrict__ b_hh,
    float* __restrict__ proj)
{
    __shared__ float Xs[32 * 34];   // [k][m], +2 pad
    __shared__ float Ws[32 * 64];   // [k][n]
    const int t  = threadIdx.x;
    const int tx = t & 15;                 // cols 4*tx..+3
    const int ty = t >> 4;                 // rows 2*ty..+1
    const int col0 = blockIdx.x * 64;
    const int row0 = blockIdx.y * 32;
    const int lr = t >> 3;                 // 0..31 load row
    const int lk = (t & 7) * 4;            // 0,4,..,28 load k

    float acc[2][4] = {};

    // prefetch chunk 0 (phase 0 = inputs/W_ih)
    float4 xv  = *(const float4*)(inp  + (size_t)(row0 + lr) * 512 + lk);
    float4 wv0 = *(const float4*)(W_ih + (size_t)(col0 + lr) * 512 + lk);
    float4 wv1 = *(const float4*)(W_ih + (size_t)(col0 + lr + 32) * 512 + lk);

    for (int cc = 0; cc < 32; ++cc) {
        __syncthreads();   // previous chunk's compute done (LDS WAR)
        Xs[(lk + 0) * 34 + lr] = xv.x;
        Xs[(lk + 1) * 34 + lr] = xv.y;
        Xs[(lk + 2) * 34 + lr] = xv.z;
        Xs[(lk + 3) * 34 + lr] = xv.w;
        Ws[(lk + 0) * 64 + lr] = wv0.x;
        Ws[(lk + 1) * 64 + lr] = wv0.y;
        Ws[(lk + 2) * 64 + lr] = wv0.z;
        Ws[(lk + 3) * 64 + lr] = wv0.w;
        Ws[(lk + 0) * 64 + lr + 32] = wv1.x;
        Ws[(lk + 1) * 64 + lr + 32] = wv1.y;
        Ws[(lk + 2) * 64 + lr + 32] = wv1.z;
        Ws[(lk + 3) * 64 + lr + 32] = wv1.w;

        // prefetch next chunk before compute (hides global latency)
        const int nc = (cc < 31) ? cc + 1 : 31;
        const float* Xg = (nc & 16) ? hid  : inp;
        const float* Wg = (nc & 16) ? W_hh : W_ih;
        const int k0 = (nc & 15) * 32;
        xv  = *(const float4*)(Xg + (size_t)(row0 + lr) * 512 + k0 + lk);
        wv0 = *(const float4*)(Wg + (size_t)(col0 + lr) * 512 + k0 + lk);
        wv1 = *(const float4*)(Wg + (size_t)(col0 + lr + 32) * 512 + k0 + lk);

        __syncthreads();   // LDS stores visible
#pragma unroll
        for (int kk = 0; kk < 32; ++kk) {
            float2 xv2 = *(const float2*)&Xs[kk * 34 + 2 * ty];
            float4 wv4 = *(const float4*)&Ws[kk * 64 + 4 * tx];
            acc[0][0] += xv2.x * wv4.x;
            acc[0][1] += xv2.x * wv4.y;
            acc[0][2] += xv2.x * wv4.z;
            acc[0][3] += xv2.x * wv4.w;
            acc[1][0] += xv2.y * wv4.x;
            acc[1][1] += xv2.y * wv4.y;
            acc[1][2] += xv2.y * wv4.z;
            acc[1][3] += xv2.y * wv4.w;
        }
    }

    const float4 bi = *(const float4*)(b_ih + col0 + 4 * tx);
    const float4 bh = *(const float4*)(b_hh + col0 + 4 * tx);
    const float4 bias = { bi.x + bh.x, bi.y + bh.y, bi.z + bh.z, bi.w + bh.w };
#pragma unroll
    for (int i = 0; i < 2; ++i) {
        const int r = row0 + 2 * ty + i;
        float4 o = { acc[i][0] + bias.x, acc[i][1] + bias.y,
                     acc[i][2] + bias.z, acc[i][3] + bias.w };
        *(float4*)(proj + (size_t)r * 1536 + col0 + 4 * tx) = o;
    }
}

// ---------------- K2: rotation (redundant per half) + 256-row matvec ----
// grid (2 halves, 256 batches), 512 thr = 8 waves; 2 blocks/CU.
__global__ __launch_bounds__(512) void matvec_half(
    const float* __restrict__ proj, const float* __restrict__ hid,
    const float* __restrict__ A, float* __restrict__ hn)
{
    __shared__ float4 Rh4[128];      // R @ hidden, 512 floats
    __shared__ float4 red[8];
    float* Rh = (float*)Rh4;

    const int half = blockIdx.x;
    const int b = blockIdx.y;
    const int t = threadIdx.x;       // 0..511, owns element t
    const float* prow = proj + (size_t)b * 1536;

    // ---- stage 1: rotation vectors, Rh = R @ h
    const float xe = prow[1024 + t];
    const float rr = prow[512 + t];
    const float hh = hid[(size_t)b * 512 + t];

    float4 p1 = { xe * xe, rr * rr, xe * rr, xe * hh };
    p1 = block_reduce4_512(p1, red, t);
    const float nx = fmaxf(sqrtf(p1.x), EPSF);
    const float nr = fmaxf(sqrtf(p1.y), EPSF);
    const float costh = p1.z / (nx * nr);
    const float sinth = sqrtf(fmaxf(1.0f - costh * costh, 0.0f));
    const float dot_ur = p1.z / nx;      // u . r
    const float a = p1.w / nx;           // u . h
    const float u = xe / nx;
    const float w = rr - dot_ur * u;

    float4 p2 = { w * w, w * hh, 0.f, 0.f };
    p2 = block_reduce4_512(p2, red, t);
    const float nw = fmaxf(sqrtf(p2.x), EPSF);
    const float bb = p2.y / nw;          // v . h
    const float v = w / nw;
    const float cm1 = costh - 1.0f;
    Rh[t] = hh + cm1 * (a * u + bb * v) + sinth * (a * v - bb * u);
    __syncthreads();

    // ---- stage 2: rows i = 256*half + 32*wv + 4*q + g, software-pipelined
    const int lane = t & 63;
    const int wv = t >> 6;               // 0..7
    const int g = lane >> 4;             // row-in-quad 0..3
    const int c = lane & 15;             // column lane

    float4 xr[8];
#pragma unroll
    for (int k = 0; k < 8; ++k) xr[k] = Rh4[c + 16 * k];

    const vfloat4* Ab = (const vfloat4*)(A + (size_t)b * 512 * 512);
    const int row_base = 256 * half + 32 * wv + g;

    vfloat4 cur[8], nxt[8];
    {
        const vfloat4* Ar = Ab + (size_t)(row_base) * 128 + c;
#pragma unroll
        for (int k = 0; k < 8; ++k)
            cur[k] = __builtin_nontemporal_load(Ar + 16 * k);
    }
#pragma unroll
    for (int q = 0; q < 8; ++q) {
        if (q < 7) {
            const vfloat4* Ar = Ab + (size_t)(row_base + 4 * (q + 1)) * 128 + c;
#pragma unroll
            for (int k = 0; k < 8; ++k)
                nxt[k] = __builtin_nontemporal_load(Ar + 16 * k);
        }
        float a0 = 0.f, a1 = 0.f;
#pragma unroll
        for (int k = 0; k < 8; k += 2) {
            a0 += cur[k].x * xr[k].x + cur[k].y * xr[k].y
                + cur[k].z * xr[k].z + cur[k].w * xr[k].w;
            a1 += cur[k + 1].x * xr[k + 1].x + cur[k + 1].y * xr[k + 1].y
                + cur[k + 1].z * xr[k + 1].z + cur[k + 1].w * xr[k + 1].w;
        }
        float accq = a0 + a1;
#pragma unroll
        for (int off = 8; off >= 1; off >>= 1)
            accq += __shfl_xor(accq, off, 16);
        if (c == 0) hn[(size_t)b * 512 + row_base + 4 * q] = accq;
#pragma unroll
        for (int k = 0; k < 8; ++k) cur[k] = nxt[k];
    }
}

// ---------------- K3: gate + relu + l2norm ------------------------------
__global__ __launch_bounds__(512) void epilogue512(
    const float* __restrict__ proj, const float* __restrict__ hid,
    const float* __restrict__ hn, float* __restrict__ out)
{
    __shared__ float4 red[8];
    const int b = blockIdx.x;
    const int t = threadIdx.x;       // owns element t
    const float* prow = proj + (size_t)b * 1536;

    const float ug = prow[t];
    const float xe = prow[1024 + t];
    const float hh = hid[(size_t)b * 512 + t];
    const float hv = hn[(size_t)b * 512 + t];

    const float cx = fmaxf(hv + xe, 0.0f);
    const float tv = ug * hh + (1.0f - ug) * cx;

    float4 p = { tv * tv, 0.f, 0.f, 0.f };
    p = block_reduce4_512(p, red, t);
    const float inv = 1.0f / fmaxf(sqrtf(p.x), EPSF);   // ETA = 1
    out[(size_t)b * 512 + t] = tv * inv;
}

extern "C" void kernel_launch(void* const* d_in, const int* in_sizes, int n_in,
                              void* d_out, int out_size, void* d_ws, size_t ws_size,
                              hipStream_t stream)
{
    const float* inp  = (const float*)d_in[0];   // [256,512]
    const float* hid  = (const float*)d_in[1];   // [256,512]
    const float* A    = (const float*)d_in[2];   // [256,512,512]
    const float* W_ih = (const float*)d_in[3];   // [1536,512]
    const float* b_ih = (const float*)d_in[4];   // [1536]
    const float* W_hh = (const float*)d_in[5];   // [1536,512]
    const float* b_hh = (const float*)d_in[6];   // [1536]
    float* out = (float*)d_out;                  // [256,512]

    float* proj = (float*)d_ws;                  // 1.5 MB
    float* hn   = proj + 256 * 1536;             // 0.5 MB

    gemm_proj<<<dim3(24, 8), 256, 0, stream>>>(inp, hid, W_ih, W_hh, b_ih, b_hh, proj);
    matvec_half<<<dim3(2, 256), 512, 0, stream>>>(proj, hid, A, hn);
    epilogue512<<<dim3(256), 512, 0, stream>>>(proj, hid, hn, out);
}